// Round 17
// baseline (19.379 us; speedup 1.0000x reference)
//
#include <hip/hip_runtime.h>
#include <math.h>

#define B_ 4096
#define D_ 256
#define C_ 64
#define BD (B_*D_)

typedef __attribute__((ext_vector_type(8))) short bf16x8;
typedef __attribute__((ext_vector_type(4))) float f32x4;

__device__ __forceinline__ float wave_reduce_sum(float v) {
    #pragma unroll
    for (int off = 1; off < 64; off <<= 1) v += __shfl_xor(v, off);
    return v;
}

__device__ __forceinline__ unsigned cvtpk(float lo, float hi) {
    unsigned r;
    asm volatile("v_cvt_pk_bf16_f32 %0, %1, %2" : "=v"(r) : "v"(lo), "v"(hi));
    return r;
}

// ---- MFMA kernel: grid = 64 conds x 4 col-quarters x 4 sample-slices = 1024 (4/CU) ----
// Block (cond,ct,sl): y[samples = sl (mod 4) of cond, cols ct*64..+63].
// ct==0 blocks also produce sum(x^2) partials from their gathered rows.
__global__ __launch_bounds__(256, 4) void k_main(const float* __restrict__ W,
                                                 const float* __restrict__ b,
                                                 const float* __restrict__ x,
                                                 const int* __restrict__ c,
                                                 float* __restrict__ out,
                                                 float* __restrict__ l1p,
                                                 float* __restrict__ xsqp,
                                                 int* __restrict__ cnt4) {
    int hw = blockIdx.x;
    int bid = (hw & 7) * 128 + (hw >> 3);   // XCD swizzle: a cond's 16 blocks share an XCD
    int cond = bid >> 4;
    int ct = (bid >> 2) & 3;
    int sl = bid & 3;
    int tid = threadIdx.x;
    int wv = tid >> 6, lane = tid & 63;
    int g = lane >> 4, fr = lane & 15;
    int r = tid >> 2, ch = tid & 3;         // W staging: row 0..63, k-chunk 0..3 (8 floats each)

    // ---- W loads FIRST (prefetch spans the scan phase), then c ----
    const float4* Wt4 = (const float4*)(W + (size_t)cond * 65536) + (size_t)(ct * 64 + r) * 64 + ch * 2;
    float4 wA[2], wB[2];
    wA[0] = Wt4[0]; wA[1] = Wt4[1];         // slab 0 (k 0..31)
    wB[0] = Wt4[8]; wB[1] = Wt4[9];         // slab 1
    int4 cvq[4];
    #pragma unroll
    for (int t = 0; t < 4; ++t) cvq[t] = ((const int4*)c)[t * 256 + tid];
    float bias_s = b[cond * 256 + ct * 64 + wv * 16 + fr];
    const float4* x4 = (const float4*)x;

    __shared__ unsigned Xl[48 * 128];        // up to 48 samples x 512B bf16 (XOR swizzled) = 24KB
    __shared__ unsigned Wl[2][64 * 20];      // dbuf W slab: 64 rows x 80B = 10KB
    __shared__ float part_x[4];
    __shared__ float part_w[4];
    __shared__ int slist[48];
    __shared__ int nlist;
    if (tid == 0) nlist = 0;
    __syncthreads();                         // bar 1: nlist init visible

    // ---- slice scan: slice sl owns samples i == sl (mod 4) (1024 candidates) ----
    #pragma unroll
    for (int t = 0; t < 4; ++t) {
        int4 q = cvq[t];
        int cc = (sl == 0) ? q.x : (sl == 1) ? q.y : (sl == 2) ? q.z : q.w;
        if (cc == cond) {
            int p = atomicAdd(&nlist, 1);
            if (p < 48) slist[p] = 4 * (t * 256 + tid) + sl;
        }
    }
    // pin W slab0 in regs
    asm volatile("" : "+v"(wA[0].x), "+v"(wA[0].y), "+v"(wA[0].z), "+v"(wA[0].w),
                      "+v"(wA[1].x), "+v"(wA[1].y), "+v"(wA[1].z), "+v"(wA[1].w));
    __syncthreads();                         // bar 2: slist ready
    int n = min(nlist, 48);
    int mts = (n + 15) >> 4;                 // 0..3 sample-tiles
    if (tid == 0 && ct == 0) cnt4[cond * 4 + sl] = n;

    // ---- stage X: batched gather; ct==0 blocks accumulate sum(x^2) ----
    int sgr[12];
    #pragma unroll
    for (int k = 0; k < 12; ++k) sgr[k] = slist[wv + 4 * k];
    float sq = 0.f;
    #pragma unroll
    for (int k = 0; k < 12; ++k) {
        int u = tid + 256 * k;
        if (u < n * 64) {
            int si = u >> 6, v = u & 63;
            float4 q = x4[(size_t)sgr[k] * 64 + v];
            int off = (v * 8) ^ ((si & 7) << 4);
            Xl[si * 128 + (off >> 2)]     = cvtpk(q.x, q.y);
            Xl[si * 128 + (off >> 2) + 1] = cvtpk(q.z, q.w);
            if (ct == 0) sq += q.x * q.x + q.y * q.y + q.z * q.z + q.w * q.w;
        }
    }
    if (ct == 0) {
        sq = wave_reduce_sum(sq);
        if (lane == 0) part_x[wv] = sq;
    }

    // ---- stage W slab0 -> buf0 ----
    float l1acc = 0.f;
    {
        uint4 pk;
        pk.x = cvtpk(wA[0].x, wA[0].y); pk.y = cvtpk(wA[0].z, wA[0].w);
        pk.z = cvtpk(wA[1].x, wA[1].y); pk.w = cvtpk(wA[1].z, wA[1].w);
        *(uint4*)(&Wl[0][r * 20 + ch * 4]) = pk;
        if (sl == 0)
            l1acc += fabsf(wA[0].x) + fabsf(wA[0].y) + fabsf(wA[0].z) + fabsf(wA[0].w)
                   + fabsf(wA[1].x) + fabsf(wA[1].y) + fabsf(wA[1].z) + fabsf(wA[1].w);
    }
    __syncthreads();                         // bar 3: Xl + Wl[0] + part_x ready
    if (tid == 0 && ct == 0)
        xsqp[cond * 4 + sl] = (part_x[0] + part_x[1]) + (part_x[2] + part_x[3]);

    // ---- K loop: 8 slabs, double-buffered ----
    f32x4 acc[3];
    #pragma unroll
    for (int mt = 0; mt < 3; ++mt) acc[mt] = (f32x4){0.f, 0.f, 0.f, 0.f};

    #pragma unroll
    for (int kk = 0; kk < 8; ++kk) {
        const unsigned* Wb = Wl[kk & 1];
        bf16x8 bfr = *(const bf16x8*)(Wb + (wv * 16 + fr) * 20 + g * 4);
        #pragma unroll
        for (int mt = 0; mt < 3; ++mt) if (mt < mts) {
            int row = mt * 16 + fr;
            bf16x8 afr = *(const bf16x8*)((const char*)Xl + row * 512 + ((kk * 64 + g * 16) ^ ((row & 7) << 4)));
            acc[mt] = __builtin_amdgcn_mfma_f32_16x16x32_bf16(afr, bfr, acc[mt], 0, 0, 0);
        }
        if (kk < 7) {
            const float4* wsrc = (kk & 1) ? wA : wB;       // slab kk+1 regs
            uint4 pk;
            pk.x = cvtpk(wsrc[0].x, wsrc[0].y); pk.y = cvtpk(wsrc[0].z, wsrc[0].w);
            pk.z = cvtpk(wsrc[1].x, wsrc[1].y); pk.w = cvtpk(wsrc[1].z, wsrc[1].w);
            *(uint4*)(&Wl[(kk + 1) & 1][r * 20 + ch * 4]) = pk;
            if (sl == 0)
                l1acc += fabsf(wsrc[0].x) + fabsf(wsrc[0].y) + fabsf(wsrc[0].z) + fabsf(wsrc[0].w)
                       + fabsf(wsrc[1].x) + fabsf(wsrc[1].y) + fabsf(wsrc[1].z) + fabsf(wsrc[1].w);
            if (kk < 6) {
                float4* wld = (kk & 1) ? wB : wA;          // reload with slab kk+2
                wld[0] = Wt4[(kk + 2) * 8];
                wld[1] = Wt4[(kk + 2) * 8 + 1];
            }
            __syncthreads();
        }
    }

    // ---- W L1 partial (sl==0 blocks; (cond,ct) quarters are disjoint) ----
    if (sl == 0) {
        float a = wave_reduce_sum(l1acc);
        if (lane == 0) part_w[wv] = a;
    }
    __syncthreads();
    if (sl == 0 && tid == 0)
        l1p[cond * 4 + ct] = (part_w[0] + part_w[1]) + (part_w[2] + part_w[3]);

    // ---- bias add + store unnormalized y ----
    #pragma unroll
    for (int mt = 0; mt < 3; ++mt) if (mt < mts) {
        #pragma unroll
        for (int j = 0; j < 4; ++j) {
            int row = mt * 16 + g * 4 + j;
            if (row < n) {
                int sg = slist[row];
                out[(size_t)sg * 256 + ct * 64 + wv * 16 + fr] = acc[mt][j] + bias_s;
            }
        }
    }
}

// ---- blocks 0..1023: row L2-normalize (wave per row) + x stripe copy ----
// ---- block 1024: finalize embed_norm and mask_norm ----
__global__ __launch_bounds__(256) void k_fin(float* __restrict__ out,
                                             const float* __restrict__ x,
                                             const float* __restrict__ xsqp,
                                             const float* __restrict__ l1p,
                                             const int* __restrict__ cnt4) {
    int tid = threadIdx.x;
    int wv = tid >> 6, lane = tid & 63;
    if (blockIdx.x == 1024) {
        __shared__ float part[4];
        float s = (tid < 256) ? xsqp[tid] : 0.f;
        s = wave_reduce_sum(s);
        if (lane == 0) part[wv] = s;
        __syncthreads();
        if (tid < 64) {
            float l1 = (l1p[tid * 4 + 0] + l1p[tid * 4 + 1]) + (l1p[tid * 4 + 2] + l1p[tid * 4 + 3]);
            float cnt = (float)((cnt4[tid * 4 + 0] + cnt4[tid * 4 + 1]) + (cnt4[tid * 4 + 2] + cnt4[tid * 4 + 3]));
            float mv = l1 * cnt;
            mv = wave_reduce_sum(mv);
            if (tid == 0) out[BD] = mv;                                               // mask_norm
        }
        if (tid == 0) out[BD + 1] = sqrtf((part[0] + part[1]) + (part[2] + part[3])); // embed_norm
        return;
    }
    // x stripe copy (independent; loads issue early, stores fire-and-forget)
    int xi = blockIdx.x * 256 + tid;
    float4 xv = ((const float4*)x)[xi];
    // row normalize: 4096 rows, wave per row
    int rowv = blockIdx.x * 4 + wv;
    float4* p = (float4*)out + (size_t)rowv * 64 + lane;
    float4 v = *p;
    float s = v.x * v.x + v.y * v.y + v.z * v.z + v.w * v.w;
    s = wave_reduce_sum(s);
    float inv = 1.0f / fmaxf(sqrtf(s), 1e-10f);
    v.x *= inv; v.y *= inv; v.z *= inv; v.w *= inv;
    *p = v;
    float2* dst = (float2*)(out + BD + 2);
    dst[2 * xi]     = make_float2(xv.x, xv.y);
    dst[2 * xi + 1] = make_float2(xv.z, xv.w);
}

extern "C" void kernel_launch(void* const* d_in, const int* in_sizes, int n_in,
                              void* d_out, int out_size, void* d_ws, size_t ws_size,
                              hipStream_t stream) {
    const float* x = (const float*)d_in[0];
    const float* W = (const float*)d_in[1];
    const float* b = (const float*)d_in[2];
    const int*   c = (const int*)d_in[3];
    float* out = (float*)d_out;

    float* xsqp = (float*)d_ws;           // 256
    float* l1p  = xsqp + 256;             // 256
    int*   cnt4 = (int*)(l1p + 256);      // 256

    k_main<<<1024, 256, 0, stream>>>(W, b, x, c, out, l1p, xsqp, cnt4);
    k_fin<<<1025, 256, 0, stream>>>(out, x, xsqp, l1p, cnt4);
}

// Round 18
// 19.208 us; speedup vs baseline: 1.0089x; 1.0089x over previous
//
#include <hip/hip_runtime.h>
#include <math.h>

#define B_ 4096
#define D_ 256
#define C_ 64
#define BD (B_*D_)

typedef __attribute__((ext_vector_type(8))) short bf16x8;
typedef __attribute__((ext_vector_type(4))) float f32x4;

__device__ __forceinline__ float wave_reduce_sum(float v) {
    #pragma unroll
    for (int off = 1; off < 64; off <<= 1) v += __shfl_xor(v, off);
    return v;
}

__device__ __forceinline__ unsigned cvtpk(float lo, float hi) {
    unsigned r;
    asm volatile("v_cvt_pk_bf16_f32 %0, %1, %2" : "=v"(r) : "v"(lo), "v"(hi));
    return r;
}

// ---- MFMA kernel: grid = 64 conds x 4 col-quarters x 4 sample-slices = 1024 (4/CU) ----
// Block (cond,ct,sl): y[samples = sl (mod 4) of cond, cols ct*64..+63].
// W slabs 0-3 preloaded in regs; one burst refill (slabs 4-7) at kk==2 ->
// only 1 of 7 K-loop barriers drains an outstanding global load (m97 fix).
__global__ __launch_bounds__(256, 4) void k_main(const float* __restrict__ W,
                                                 const float* __restrict__ b,
                                                 const float* __restrict__ x,
                                                 const int* __restrict__ c,
                                                 float* __restrict__ out,
                                                 float* __restrict__ l1p,
                                                 float* __restrict__ xsqp,
                                                 int* __restrict__ cnt4) {
    int hw = blockIdx.x;
    int bid = (hw & 7) * 128 + (hw >> 3);   // XCD swizzle: a cond's 16 blocks share an XCD
    int cond = bid >> 4;
    int ct = (bid >> 2) & 3;
    int sl = bid & 3;
    int tid = threadIdx.x;
    int wv = tid >> 6, lane = tid & 63;
    int g = lane >> 4, fr = lane & 15;
    int r = tid >> 2, ch = tid & 3;         // W staging: row 0..63, k-chunk 0..3 (8 floats each)

    // ---- early independent loads: x stripe, c slice, W slabs 0..3, bias ----
    const float4* x4 = (const float4*)x;
    int xi = bid * 256 + tid;               // 1 float4 per thread
    float4 xv = x4[xi];
    int4 cvq[4];
    #pragma unroll
    for (int t = 0; t < 4; ++t) cvq[t] = ((const int4*)c)[t * 256 + tid];
    const float4* Wt4 = (const float4*)(W + (size_t)cond * 65536) + (size_t)(ct * 64 + r) * 64 + ch * 2;
    float4 wS[4][2];
    #pragma unroll
    for (int s2 = 0; s2 < 4; ++s2) { wS[s2][0] = Wt4[s2 * 8]; wS[s2][1] = Wt4[s2 * 8 + 1]; }
    float bias_s = b[cond * 256 + ct * 64 + wv * 16 + fr];

    __shared__ unsigned Xl[48 * 128];        // up to 48 samples x 512B bf16 (XOR swizzled) = 24KB
    __shared__ unsigned Wl[2][64 * 20];      // dbuf W slab: 64 rows x 80B = 10KB
    __shared__ float part_x[4];
    __shared__ float part_w[4];
    __shared__ int slist[48];
    __shared__ int nlist;
    if (tid == 0) nlist = 0;

    // ---- x copy to out tail + sumsq partial ----
    float2* dst = (float2*)(out + BD + 2);
    dst[2 * xi]     = make_float2(xv.x, xv.y);
    dst[2 * xi + 1] = make_float2(xv.z, xv.w);
    float s = xv.x * xv.x + xv.y * xv.y + xv.z * xv.z + xv.w * xv.w;
    s = wave_reduce_sum(s);
    if (lane == 0) part_x[wv] = s;
    __syncthreads();                         // bar 1: nlist init + part_x visible

    // ---- slice scan: slice sl owns samples i == sl (mod 4) (1024 candidates) ----
    #pragma unroll
    for (int t = 0; t < 4; ++t) {
        int4 q = cvq[t];
        int cc = (sl == 0) ? q.x : (sl == 1) ? q.y : (sl == 2) ? q.z : q.w;
        if (cc == cond) {
            int p = atomicAdd(&nlist, 1);
            if (p < 48) slist[p] = 4 * (t * 256 + tid) + sl;
        }
    }
    // pin preloaded W slabs (loads issued early; don't let compiler re-sink them)
    #pragma unroll
    for (int s2 = 0; s2 < 4; ++s2) {
        asm volatile("" : "+v"(wS[s2][0].x), "+v"(wS[s2][0].y), "+v"(wS[s2][0].z), "+v"(wS[s2][0].w),
                          "+v"(wS[s2][1].x), "+v"(wS[s2][1].y), "+v"(wS[s2][1].z), "+v"(wS[s2][1].w));
    }
    __syncthreads();                         // bar 2: slist ready
    int n = min(nlist, 48);
    int mts = (n + 15) >> 4;                 // 0..3 sample-tiles
    if (tid == 0) {
        xsqp[bid] = (part_x[0] + part_x[1]) + (part_x[2] + part_x[3]);
        if (ct == 0) cnt4[cond * 4 + sl] = n;
    }

    // ---- stage X: batched gather (slist pre-read -> all loads in flight) ----
    int sgr[12];
    #pragma unroll
    for (int k = 0; k < 12; ++k) sgr[k] = slist[wv + 4 * k];
    #pragma unroll
    for (int k = 0; k < 12; ++k) {
        int u = tid + 256 * k;
        if (u < n * 64) {
            int si = u >> 6, v = u & 63;
            float4 q = x4[(size_t)sgr[k] * 64 + v];
            int off = (v * 8) ^ ((si & 7) << 4);
            Xl[si * 128 + (off >> 2)]     = cvtpk(q.x, q.y);
            Xl[si * 128 + (off >> 2) + 1] = cvtpk(q.z, q.w);
        }
    }

    // ---- stage W slab0 -> buf0 ----
    float l1acc = 0.f;
    {
        uint4 pk;
        pk.x = cvtpk(wS[0][0].x, wS[0][0].y); pk.y = cvtpk(wS[0][0].z, wS[0][0].w);
        pk.z = cvtpk(wS[0][1].x, wS[0][1].y); pk.w = cvtpk(wS[0][1].z, wS[0][1].w);
        *(uint4*)(&Wl[0][r * 20 + ch * 4]) = pk;
        if (sl == 0)
            l1acc += fabsf(wS[0][0].x) + fabsf(wS[0][0].y) + fabsf(wS[0][0].z) + fabsf(wS[0][0].w)
                   + fabsf(wS[0][1].x) + fabsf(wS[0][1].y) + fabsf(wS[0][1].z) + fabsf(wS[0][1].w);
    }
    __syncthreads();                         // bar 3: Xl + Wl[0] ready

    // ---- K loop: 8 slabs, double-buffered; regs hold 4 slabs, burst refill at kk==2 ----
    f32x4 acc[3];
    #pragma unroll
    for (int mt = 0; mt < 3; ++mt) acc[mt] = (f32x4){0.f, 0.f, 0.f, 0.f};

    #pragma unroll
    for (int kk = 0; kk < 8; ++kk) {
        const unsigned* Wb = Wl[kk & 1];
        bf16x8 bfr = *(const bf16x8*)(Wb + (wv * 16 + fr) * 20 + g * 4);
        #pragma unroll
        for (int mt = 0; mt < 3; ++mt) if (mt < mts) {
            int row = mt * 16 + fr;
            bf16x8 afr = *(const bf16x8*)((const char*)Xl + row * 512 + ((kk * 64 + g * 16) ^ ((row & 7) << 4)));
            acc[mt] = __builtin_amdgcn_mfma_f32_16x16x32_bf16(afr, bfr, acc[mt], 0, 0, 0);
        }
        if (kk < 7) {
            float4 w0 = wS[(kk + 1) & 3][0];
            float4 w1 = wS[(kk + 1) & 3][1];
            uint4 pk;
            pk.x = cvtpk(w0.x, w0.y); pk.y = cvtpk(w0.z, w0.w);
            pk.z = cvtpk(w1.x, w1.y); pk.w = cvtpk(w1.z, w1.w);
            *(uint4*)(&Wl[(kk + 1) & 1][r * 20 + ch * 4]) = pk;
            if (sl == 0)
                l1acc += fabsf(w0.x) + fabsf(w0.y) + fabsf(w0.z) + fabsf(w0.w)
                       + fabsf(w1.x) + fabsf(w1.y) + fabsf(w1.z) + fabsf(w1.w);
            if (kk == 2) {                   // burst refill: slabs 4..7 (one draining barrier)
                #pragma unroll
                for (int s2 = 0; s2 < 4; ++s2) {
                    wS[s2][0] = Wt4[(4 + s2) * 8];
                    wS[s2][1] = Wt4[(4 + s2) * 8 + 1];
                }
            }
            __syncthreads();
        }
    }

    // ---- W L1 partial (sl==0 blocks; (cond,ct) quarters are disjoint) ----
    if (sl == 0) {
        float a = wave_reduce_sum(l1acc);
        if (lane == 0) part_w[wv] = a;
    }
    __syncthreads();
    if (sl == 0 && tid == 0)
        l1p[cond * 4 + ct] = (part_w[0] + part_w[1]) + (part_w[2] + part_w[3]);

    // ---- bias add + store unnormalized y ----
    #pragma unroll
    for (int mt = 0; mt < 3; ++mt) if (mt < mts) {
        #pragma unroll
        for (int j = 0; j < 4; ++j) {
            int row = mt * 16 + g * 4 + j;
            if (row < n) {
                int sg = slist[row];
                out[(size_t)sg * 256 + ct * 64 + wv * 16 + fr] = acc[mt][j] + bias_s;
            }
        }
    }
}

// ---- blocks 0..1023: row L2-normalize (wave per row) ----
// ---- block 1024: finalize embed_norm and mask_norm ----
__global__ __launch_bounds__(256) void k_fin(float* __restrict__ out,
                                             const float* __restrict__ xsqp,
                                             const float* __restrict__ l1p,
                                             const int* __restrict__ cnt4) {
    int tid = threadIdx.x;
    int wv = tid >> 6, lane = tid & 63;
    if (blockIdx.x == 1024) {
        __shared__ float part[4];
        float s = 0.f;
        #pragma unroll
        for (int j = 0; j < 4; ++j) s += xsqp[tid * 4 + j];
        s = wave_reduce_sum(s);
        if (lane == 0) part[wv] = s;
        __syncthreads();
        if (tid < 64) {
            float l1 = (l1p[tid * 4 + 0] + l1p[tid * 4 + 1]) + (l1p[tid * 4 + 2] + l1p[tid * 4 + 3]);
            float cnt = (float)((cnt4[tid * 4 + 0] + cnt4[tid * 4 + 1]) + (cnt4[tid * 4 + 2] + cnt4[tid * 4 + 3]));
            float mv = l1 * cnt;
            mv = wave_reduce_sum(mv);
            if (tid == 0) out[BD] = mv;                                               // mask_norm
        }
        if (tid == 0) out[BD + 1] = sqrtf((part[0] + part[1]) + (part[2] + part[3])); // embed_norm
        return;
    }
    int rowv = blockIdx.x * 4 + wv;          // 4096 rows, wave per row
    float4* p = (float4*)out + (size_t)rowv * 64 + lane;
    float4 v = *p;
    float s = v.x * v.x + v.y * v.y + v.z * v.z + v.w * v.w;
    s = wave_reduce_sum(s);
    float inv = 1.0f / fmaxf(sqrtf(s), 1e-10f);
    v.x *= inv; v.y *= inv; v.z *= inv; v.w *= inv;
    *p = v;
}

extern "C" void kernel_launch(void* const* d_in, const int* in_sizes, int n_in,
                              void* d_out, int out_size, void* d_ws, size_t ws_size,
                              hipStream_t stream) {
    const float* x = (const float*)d_in[0];
    const float* W = (const float*)d_in[1];
    const float* b = (const float*)d_in[2];
    const int*   c = (const int*)d_in[3];
    float* out = (float*)d_out;

    float* xsqp = (float*)d_ws;           // 1024
    float* l1p  = xsqp + 1024;            // 256
    int*   cnt4 = (int*)(l1p + 256);      // 256

    k_main<<<1024, 256, 0, stream>>>(W, b, x, c, out, l1p, xsqp, cnt4);
    k_fin<<<1025, 256, 0, stream>>>(out, xsqp, l1p, cnt4);
}

// Round 19
// 18.449 us; speedup vs baseline: 1.0504x; 1.0411x over previous
//
#include <hip/hip_runtime.h>
#include <math.h>

#define B_ 4096
#define D_ 256
#define C_ 64
#define BD (B_*D_)

typedef __attribute__((ext_vector_type(8))) short bf16x8;
typedef __attribute__((ext_vector_type(4))) float f32x4;

__device__ __forceinline__ float wave_reduce_sum(float v) {
    #pragma unroll
    for (int off = 1; off < 64; off <<= 1) v += __shfl_xor(v, off);
    return v;
}

__device__ __forceinline__ unsigned cvtpk(float lo, float hi) {
    unsigned r;
    asm volatile("v_cvt_pk_bf16_f32 %0, %1, %2" : "=v"(r) : "v"(lo), "v"(hi));
    return r;
}

// ---- MFMA kernel: grid = 64 conds x 4 col-quarters x 4 sample-slices = 1024 (4/CU) ----
// Block (cond,ct,sl): y[samples = sl (mod 4) of cond, cols ct*64..+63].
__global__ __launch_bounds__(256, 4) void k_main(const float* __restrict__ W,
                                                 const float* __restrict__ b,
                                                 const float* __restrict__ x,
                                                 const int* __restrict__ c,
                                                 float* __restrict__ out,
                                                 float* __restrict__ l1p,
                                                 float* __restrict__ xsqp,
                                                 int* __restrict__ cnt4) {
    int hw = blockIdx.x;
    int bid = (hw & 7) * 128 + (hw >> 3);   // XCD swizzle: a cond's 16 blocks share an XCD
    int cond = bid >> 4;
    int ct = (bid >> 2) & 3;
    int sl = bid & 3;
    int tid = threadIdx.x;
    int wv = tid >> 6, lane = tid & 63;
    int g = lane >> 4, fr = lane & 15;
    int r = tid >> 2, ch = tid & 3;         // W staging: row 0..63, k-chunk 0..3 (8 floats each)

    // ---- early independent loads: x stripe, c slice, W slab0, bias ----
    const float4* x4 = (const float4*)x;
    int xi = bid * 256 + tid;               // 1 float4 per thread
    float4 xv = x4[xi];
    int4 cvq[4];
    #pragma unroll
    for (int t = 0; t < 4; ++t) cvq[t] = ((const int4*)c)[t * 256 + tid];
    // this block's W rows: cond*65536 + (ct*64 + r)*256 floats; slab kk float4 base kk*8 + ch*2
    const float4* Wt4 = (const float4*)(W + (size_t)cond * 65536) + (size_t)(ct * 64 + r) * 64 + ch * 2;
    float4 wA[2], wB[2];
    wA[0] = Wt4[0]; wA[1] = Wt4[1];         // slab 0 (k 0..31)
    float bias_s = b[cond * 256 + ct * 64 + wv * 16 + fr];

    __shared__ unsigned Xl[48 * 128];        // up to 48 samples x 512B bf16 (XOR swizzled) = 24KB
    __shared__ unsigned Wl[2][64 * 20];      // dbuf W slab: 64 rows x 80B = 10KB
    __shared__ float part_x[4];
    __shared__ float part_w[4];
    __shared__ int slist[48];
    __shared__ int nlist;
    if (tid == 0) nlist = 0;

    // ---- x copy to out tail + sumsq partial ----
    float2* dst = (float2*)(out + BD + 2);
    dst[2 * xi]     = make_float2(xv.x, xv.y);
    dst[2 * xi + 1] = make_float2(xv.z, xv.w);
    float s = xv.x * xv.x + xv.y * xv.y + xv.z * xv.z + xv.w * xv.w;
    s = wave_reduce_sum(s);
    if (lane == 0) part_x[wv] = s;
    __syncthreads();                         // nlist init + part_x visible

    // ---- slice scan: slice sl owns samples i == sl (mod 4) (1024 candidates) ----
    #pragma unroll
    for (int t = 0; t < 4; ++t) {
        int4 q = cvq[t];
        int cc = (sl == 0) ? q.x : (sl == 1) ? q.y : (sl == 2) ? q.z : q.w;
        if (cc == cond) {
            int p = atomicAdd(&nlist, 1);
            if (p < 48) slist[p] = 4 * (t * 256 + tid) + sl;
        }
    }
    // pin W slab0 in regs
    asm volatile("" : "+v"(wA[0].x), "+v"(wA[0].y), "+v"(wA[0].z), "+v"(wA[0].w),
                      "+v"(wA[1].x), "+v"(wA[1].y), "+v"(wA[1].z), "+v"(wA[1].w));
    __syncthreads();
    int n = min(nlist, 48);
    int mts = (n + 15) >> 4;                 // 0..3 sample-tiles
    if (tid == 0) {
        xsqp[bid] = (part_x[0] + part_x[1]) + (part_x[2] + part_x[3]);
        if (ct == 0) cnt4[cond * 4 + sl] = n;
    }

    // ---- stage X: batched gather (slist pre-read -> all loads in flight) ----
    int sgr[12];
    #pragma unroll
    for (int k = 0; k < 12; ++k) sgr[k] = slist[wv + 4 * k];
    #pragma unroll
    for (int k = 0; k < 12; ++k) {
        int u = tid + 256 * k;
        if (u < n * 64) {
            int si = u >> 6, v = u & 63;
            float4 q = x4[(size_t)sgr[k] * 64 + v];
            int off = (v * 8) ^ ((si & 7) << 4);
            Xl[si * 128 + (off >> 2)]     = cvtpk(q.x, q.y);
            Xl[si * 128 + (off >> 2) + 1] = cvtpk(q.z, q.w);
        }
    }

    // ---- stage W slab0 -> buf0, prefetch slab1 ----
    float l1acc = 0.f;
    {
        uint4 pk;
        pk.x = cvtpk(wA[0].x, wA[0].y); pk.y = cvtpk(wA[0].z, wA[0].w);
        pk.z = cvtpk(wA[1].x, wA[1].y); pk.w = cvtpk(wA[1].z, wA[1].w);
        *(uint4*)(&Wl[0][r * 20 + ch * 4]) = pk;
        if (sl == 0)
            l1acc += fabsf(wA[0].x) + fabsf(wA[0].y) + fabsf(wA[0].z) + fabsf(wA[0].w)
                   + fabsf(wA[1].x) + fabsf(wA[1].y) + fabsf(wA[1].z) + fabsf(wA[1].w);
    }
    wB[0] = Wt4[8]; wB[1] = Wt4[9];          // slab 1
    __syncthreads();                         // Xl + Wl[0] ready

    // ---- K loop: 8 slabs, double-buffered ----
    f32x4 acc[3];
    #pragma unroll
    for (int mt = 0; mt < 3; ++mt) acc[mt] = (f32x4){0.f, 0.f, 0.f, 0.f};

    #pragma unroll
    for (int kk = 0; kk < 8; ++kk) {
        const unsigned* Wb = Wl[kk & 1];
        bf16x8 bfr = *(const bf16x8*)(Wb + (wv * 16 + fr) * 20 + g * 4);
        #pragma unroll
        for (int mt = 0; mt < 3; ++mt) if (mt < mts) {
            int row = mt * 16 + fr;
            bf16x8 afr = *(const bf16x8*)((const char*)Xl + row * 512 + ((kk * 64 + g * 16) ^ ((row & 7) << 4)));
            acc[mt] = __builtin_amdgcn_mfma_f32_16x16x32_bf16(afr, bfr, acc[mt], 0, 0, 0);
        }
        if (kk < 7) {
            const float4* wsrc = (kk & 1) ? wA : wB;       // slab kk+1 regs
            uint4 pk;
            pk.x = cvtpk(wsrc[0].x, wsrc[0].y); pk.y = cvtpk(wsrc[0].z, wsrc[0].w);
            pk.z = cvtpk(wsrc[1].x, wsrc[1].y); pk.w = cvtpk(wsrc[1].z, wsrc[1].w);
            *(uint4*)(&Wl[(kk + 1) & 1][r * 20 + ch * 4]) = pk;
            if (sl == 0)
                l1acc += fabsf(wsrc[0].x) + fabsf(wsrc[0].y) + fabsf(wsrc[0].z) + fabsf(wsrc[0].w)
                       + fabsf(wsrc[1].x) + fabsf(wsrc[1].y) + fabsf(wsrc[1].z) + fabsf(wsrc[1].w);
            if (kk < 6) {
                float4* wld = (kk & 1) ? wB : wA;          // reload with slab kk+2
                wld[0] = Wt4[(kk + 2) * 8];
                wld[1] = Wt4[(kk + 2) * 8 + 1];
            }
            __syncthreads();
        }
    }

    // ---- W L1 partial (sl==0 blocks; (cond,ct) quarters are disjoint) ----
    if (sl == 0) {
        float a = wave_reduce_sum(l1acc);
        if (lane == 0) part_w[wv] = a;
    }
    __syncthreads();
    if (sl == 0 && tid == 0)
        l1p[cond * 4 + ct] = (part_w[0] + part_w[1]) + (part_w[2] + part_w[3]);

    // ---- bias add + store unnormalized y ----
    #pragma unroll
    for (int mt = 0; mt < 3; ++mt) if (mt < mts) {
        #pragma unroll
        for (int j = 0; j < 4; ++j) {
            int row = mt * 16 + g * 4 + j;
            if (row < n) {
                int sg = slist[row];
                out[(size_t)sg * 256 + ct * 64 + wv * 16 + fr] = acc[mt][j] + bias_s;
            }
        }
    }
}

// ---- blocks 0..1023: row L2-normalize (wave per row) ----
// ---- block 1024: finalize embed_norm and mask_norm ----
__global__ __launch_bounds__(256) void k_fin(float* __restrict__ out,
                                             const float* __restrict__ xsqp,
                                             const float* __restrict__ l1p,
                                             const int* __restrict__ cnt4) {
    int tid = threadIdx.x;
    int wv = tid >> 6, lane = tid & 63;
    if (blockIdx.x == 1024) {
        __shared__ float part[4];
        float s = 0.f;
        #pragma unroll
        for (int j = 0; j < 4; ++j) s += xsqp[tid * 4 + j];
        s = wave_reduce_sum(s);
        if (lane == 0) part[wv] = s;
        __syncthreads();
        if (tid < 64) {
            float l1 = (l1p[tid * 4 + 0] + l1p[tid * 4 + 1]) + (l1p[tid * 4 + 2] + l1p[tid * 4 + 3]);
            float cnt = (float)((cnt4[tid * 4 + 0] + cnt4[tid * 4 + 1]) + (cnt4[tid * 4 + 2] + cnt4[tid * 4 + 3]));
            float mv = l1 * cnt;
            mv = wave_reduce_sum(mv);
            if (tid == 0) out[BD] = mv;                                               // mask_norm
        }
        if (tid == 0) out[BD + 1] = sqrtf((part[0] + part[1]) + (part[2] + part[3])); // embed_norm
        return;
    }
    int rowv = blockIdx.x * 4 + wv;          // 4096 rows, wave per row
    float4* p = (float4*)out + (size_t)rowv * 64 + lane;
    float4 v = *p;
    float s = v.x * v.x + v.y * v.y + v.z * v.z + v.w * v.w;
    s = wave_reduce_sum(s);
    float inv = 1.0f / fmaxf(sqrtf(s), 1e-10f);
    v.x *= inv; v.y *= inv; v.z *= inv; v.w *= inv;
    *p = v;
}

extern "C" void kernel_launch(void* const* d_in, const int* in_sizes, int n_in,
                              void* d_out, int out_size, void* d_ws, size_t ws_size,
                              hipStream_t stream) {
    const float* x = (const float*)d_in[0];
    const float* W = (const float*)d_in[1];
    const float* b = (const float*)d_in[2];
    const int*   c = (const int*)d_in[3];
    float* out = (float*)d_out;

    float* xsqp = (float*)d_ws;           // 1024
    float* l1p  = xsqp + 1024;            // 256
    int*   cnt4 = (int*)(l1p + 256);      // 256

    k_main<<<1024, 256, 0, stream>>>(W, b, x, c, out, l1p, xsqp, cnt4);
    k_fin<<<1025, 256, 0, stream>>>(out, xsqp, l1p, cnt4);
}